// Round 1
// baseline (162.481 us; speedup 1.0000x reference)
//
#include <hip/hip_runtime.h>
#include <hip/hip_fp16.h>
#include <math.h>

// ============================================================================
// MAXSAT mixing, round 1: split-f16 MFMA for the coordinate-descent dots.
//
// Structure:
//  kernel1 (compute_C): Gram rows C[v][*] (row i = var v=i+1), with cols
//    jj=(i-u) mod 64, u=0..5 PRE-ZEROED (diag + 5 deferred), plus tables
//    c0[i]=C[v][0] and d_u[i]=C[v][((i-u)%64)+1], u=1..5.
//  mixing: per 4-step group G, Q[4 steps][12 k] = (4x64)*(64x12) computed by
//    12 chained v_mfma_f32_16x16x16f16 over 4 K-chunks of 16 vars:
//        D += Ch*Vh + Ch*Vl + Cl*Vh        (split-f16: ~f32 accuracy)
//    MFMA(G+1) is issued between steps 4G+1 and 4G+2; prezero width 6 +
//    f32 carries vp1..vp5 (corrections d_u[i]*vp_u, d_u via v_readlane from
//    lane-distributed VGPR tables) make this EXACT Gauss-Seidel.
//
// Fragment layouts (v_mfma_f32_16x16x16f16, AMD matrix-calculator maps):
//   A[m][k]: lane l, elem e: m = l%16, k = 4*(l/16)+e
//   B[k][n]: lane l, elem e: k = 4*(l/16)+e, n = l%16
//   D[m][n]: lane l, reg  r: m = 4*(l/16)+r, n = l%16
// We set m = step row, k = var-within-chunk, n = kdim slot (12 of 16 used;
// slots 12..15 are exactly 0 end-to-end). A rows are stored once and
// REPLICATED mod 4 via the read address ((l&3)*32), so D[r] = Q[step r][n]
// in EVERY lane: no bpermute, v_new[k] is born in lane k of each 16-row.
//   >>> If this round returns garbage absmax (~O(0.1+)), the suspect is the
//   >>> A/B lane->k map or A-arg transpose; flip m<->k in the frag-build.
//
// f32 shadow of the k=0 component feeds the acos output path (full f32).
// ============================================================================

#define BATCH 1024
#define NV    64
#define MC    256
#define KD    12
#define PI_F  3.14159265358979323846f

// compact C layout (floats, per m-split copy):
//   [0,4352): row i x 68: slot jj = C[i+1][jj+1], zeroed for (i-jj)%64 <= 5
//   [C0OFF+i): c0[i]   [DGOFF+(u-1)*64+i): d_u[i]
#define C0OFF 4352
#define DGOFF 4416
#define CBUF  4736

typedef float v4f __attribute__((ext_vector_type(4)));
typedef _Float16 v4h __attribute__((ext_vector_type(4)));
typedef unsigned int u2v __attribute__((ext_vector_type(2)));

// ---- DPP add helpers (canonical fusable form) ----
template <int CTRL>
__device__ __forceinline__ float dpp_addf(float x) {
  int y = __builtin_amdgcn_update_dpp(0, __float_as_int(x), CTRL, 0xF, 0xF, true);
  return x + __int_as_float(y);
}
__device__ __forceinline__ float allreduce16(float x) {
  x = dpp_addf<0xB1>(x);   // quad xor1
  x = dpp_addf<0x4E>(x);   // quad xor2
  x = dpp_addf<0x124>(x);  // row_ror:4
  x = dpp_addf<0x128>(x);  // row_ror:8
  return x;
}
__device__ __forceinline__ float rlane(float x, int lane) {
  return __int_as_float(__builtin_amdgcn_readlane(__float_as_int(x), lane));
}

// ---- Kernel 1: Gram rows with 6-col prezero + c0/d1..d5 tables ----
__global__ void compute_C_kernel(const float* __restrict__ S,
                                 const float* __restrict__ w,
                                 float* __restrict__ Cg, int nsplit) {
  const int i = blockIdx.x;   // row i = var v = i+1
  const int mc = blockIdx.y;
  const int j = threadIdx.x;  // S-space column 0..64
  if (j > NV) return;
  const int v = i + 1;
  const int mlen = MC / nsplit;
  const int m0 = mc * mlen;
  float a0 = 0.f, a1 = 0.f, a2 = 0.f, a3 = 0.f;
  for (int m = m0; m < m0 + mlen; m += 4) {
    const float w0 = w[m], w1 = w[m + 1], w2 = w[m + 2], w3 = w[m + 3];
    a0 = fmaf(S[(m + 0) * (NV + 1) + v] * w0 * w0, S[(m + 0) * (NV + 1) + j], a0);
    a1 = fmaf(S[(m + 1) * (NV + 1) + v] * w1 * w1, S[(m + 1) * (NV + 1) + j], a1);
    a2 = fmaf(S[(m + 2) * (NV + 1) + v] * w2 * w2, S[(m + 2) * (NV + 1) + j], a2);
    a3 = fmaf(S[(m + 3) * (NV + 1) + v] * w3 * w3, S[(m + 3) * (NV + 1) + j], a3);
  }
  const float acc = (a0 + a1) + (a2 + a3);
  float* buf = Cg + mc * CBUF;
  if (j == 0) {
    buf[C0OFF + i] = acc;
  } else {
    const int jj = j - 1;                  // 0-based var column
    const int du = (i - jj + 64) & 63;     // deferral distance
    if (du >= 1 && du <= 5) buf[DGOFF + (du - 1) * 64 + i] = acc;
    buf[i * 68 + jj] = (du <= 5) ? 0.f : acc;
  }
}

// ---- Kernel 2: MFMA mixing -------------------------------------------------
// Block = 256 thr = 4 waves = 4 batches. Per wave: lane l, n = l&15 (kdim),
// lg = l>>4 (k-chunk quarter / A row-copy index).
__global__ __launch_bounds__(256, 1) void mixing_kernel(
    const float* __restrict__ z, const float* __restrict__ r,
    const float* __restrict__ Cg, const int* __restrict__ max_iter_p,
    float* __restrict__ out, int nsplit) {
  __shared__ __align__(16) float Lc[CBUF];            // 18944 B compact C
  __shared__ __align__(16) unsigned short La[8192];   // 16384 B A-frags (f16)

  const int t = threadIdx.x;
  const int l = t & 63;
  const int n = l & 15;
  const int lg = l >> 4;
  const int b = blockIdx.x * 4 + (t >> 6);
  const int max_iter = max_iter_p[0];

  // ---- stage (and m-split-reduce) compact C into LDS ----
  {
    const float4* src = (const float4*)Cg;
    float4* dst = (float4*)Lc;
    for (int idx = t; idx < CBUF / 4; idx += 256) {
      float4 a = src[idx];
      for (int u = 1; u < nsplit; ++u) {
        const float4 p = src[u * (CBUF / 4) + idx];
        a.x += p.x; a.y += p.y; a.z += p.z; a.w += p.w;
      }
      dst[idx] = a;
    }
  }

  // ---- V-init in B-frag layout (split f16 hi/lo), f32 shadow, carries ----
  // chunk c, reg ep, half eh: var = 16c + 4*lg + (2*ep+eh), kdim = n.
  unsigned int Vh[4][2], Vl[4][2];
  #pragma unroll
  for (int c = 0; c < 4; ++c) {
    #pragma unroll
    for (int ep = 0; ep < 2; ++ep) {
      unsigned int hh = 0, ll = 0;
      #pragma unroll
      for (int eh = 0; eh < 2; ++eh) {
        const int var = 16 * c + 4 * lg + 2 * ep + eh;
        const float zv = z[b * NV + var];
        float rp = 0.f;
        if (n >= 1 && n < KD) rp = r[(b * NV + var) * KD + n];
        const float ssp = allreduce16(rp * rp);
        const float inv = 1.f / fmaxf(sqrtf(ssp), 1e-8f);
        const float sn = __builtin_amdgcn_sinf(0.5f * zv);  // sin(pi*z)
        const float cs = __builtin_amdgcn_cosf(0.5f * zv);  // cos(pi*z)
        const float vv = (n == 0) ? -cs : sn * rp * inv;    // n>=12 -> 0
        const unsigned int h16 = __half_as_ushort(__float2half(vv));
        const float hf = __half2float(__ushort_as_half((unsigned short)h16));
        const unsigned int l16 = __half_as_ushort(__float2half(vv - hf));
        hh |= h16 << (16 * eh);
        ll |= l16 << (16 * eh);
      }
      Vh[c][ep] = hh;
      Vl[c][ep] = ll;
    }
  }
  // f32 shadow of k=0 comps: sh[p] holds var 16p + (l&15)
  float sh[4];
  #pragma unroll
  for (int p = 0; p < 4; ++p) {
    const float zv = z[b * NV + 16 * p + n];
    sh[p] = -__builtin_amdgcn_cosf(0.5f * zv);
  }
  // carries: vp0 = e0 indicator; vp1..vp5 = V_init[63..59][n]
  float vp[6];
  vp[0] = (n == 0) ? 1.f : 0.f;
  #pragma unroll
  for (int u = 1; u <= 5; ++u) {
    const int var = NV - u;
    const float zv = z[b * NV + var];
    float rp = 0.f;
    if (n >= 1 && n < KD) rp = r[(b * NV + var) * KD + n];
    const float ssp = allreduce16(rp * rp);
    const float inv = 1.f / fmaxf(sqrtf(ssp), 1e-8f);
    const float sn = __builtin_amdgcn_sinf(0.5f * zv);
    const float cs = __builtin_amdgcn_cosf(0.5f * zv);
    vp[u] = (n == 0) ? -cs : sn * rp * inv;
  }

  __syncthreads();

  // ---- one-time: build A-frags (f16 split) from compact C ----
  // dest block (G*4+c)*2+p : 64 ushorts = rows m(0..3) x lanegrp(0..3) x e(0..3)
  for (int e16 = 0; e16 < 16; ++e16) {
    const int idx = e16 * 256 + t;
    const int ri = idx >> 6, jj = idx & 63;
    const float f = Lc[ri * 68 + jj];
    const __half h = __float2half(f);
    const float hf = __half2float(h);
    const __half lo = __float2half(f - hf);
    const int G = ri >> 2, m = ri & 3, c = jj >> 4, jc = jj & 15;
    const int off = ((G * 4 + c) * 2) * 64 + m * 16 + (jc >> 2) * 4 + (jc & 3);
    La[off] = __half_as_ushort(h);
    La[off + 64] = __half_as_ushort(lo);
  }
  // lane-distributed tables: lane l holds c0[l], d1[l]..d5[l]
  const float t0v = Lc[C0OFF + l];
  const float t1v = Lc[DGOFF + 0 * 64 + l];
  const float t2v = Lc[DGOFF + 1 * 64 + l];
  const float t3v = Lc[DGOFF + 2 * 64 + l];
  const float t4v = Lc[DGOFF + 3 * 64 + l];
  const float t5v = Lc[DGOFF + 4 * 64 + l];

  __syncthreads();

  // per-lane A read offset (ushort units): row-replication via (l&3)
  const int aoff = (l & 3) * 16 + lg * 4;

  u2v AH[4], AL[4];
  auto LOADA = [&](int Gn) {
    #pragma unroll
    for (int c = 0; c < 4; ++c) {
      const int blk = ((Gn * 4 + c) * 2) * 64;
      AH[c] = *(const u2v*)(&La[blk + aoff]);
      AL[c] = *(const u2v*)(&La[blk + 64 + aoff]);
    }
  };
  auto MF = [&](u2v a, unsigned int b0, unsigned int b1, v4f acc) -> v4f {
    u2v bv; bv.x = b0; bv.y = b1;
    return __builtin_amdgcn_mfma_f32_16x16x16f16(
        __builtin_bit_cast(v4h, a), __builtin_bit_cast(v4h, bv), acc, 0, 0, 0);
  };
  auto MFMA12 = [&](v4f acc) -> v4f {
    #pragma unroll
    for (int c = 0; c < 4; ++c) {
      acc = MF(AH[c], Vh[c][0], Vh[c][1], acc);  // Ch*Vh
      acc = MF(AH[c], Vl[c][0], Vl[c][1], acc);  // Ch*Vl
      acc = MF(AL[c], Vh[c][0], Vh[c][1], acc);  // Cl*Vh
    }
    return acc;
  };

  // ---- per-step serial tail: corrections, norm, writeback ----
  auto TAIL = [&](int i, float q) {
    const float d0 = rlane(t0v, i), d1 = rlane(t1v, i), d2 = rlane(t2v, i);
    const float d3 = rlane(t3v, i), d4 = rlane(t4v, i), d5 = rlane(t5v, i);
    // g = q + sum d_u*vp_u (shallow tree to cut serial depth)
    float ga = fmaf(d1, vp[1], fmaf(d0, vp[0], q));
    float gb = fmaf(d3, vp[3], d2 * vp[2]);
    float gc = fmaf(d5, vp[5], d4 * vp[4]);
    const float g = ga + (gb + gc);
    float n2 = allreduce16(g * g);           // sum over kdim (row-local)
    const float inv = __builtin_amdgcn_rsqf(fmaxf(n2, 1e-16f));
    const float vn = -g * inv;               // v_new[kdim n], all lanes real
    // f32 shadow of k=0
    const float v0 = rlane(vn, 0);
    {
      const int pg = i >> 4, ip = i & 15;
      sh[pg] = (n == ip) ? v0 : sh[pg];
    }
    // split-f16 writeback into B-frag (static chunk/reg/half, owner-masked)
    const unsigned int h16 = (unsigned int)__half_as_ushort(__float2half(vn));
    const float hf = __half2float(__ushort_as_half((unsigned short)h16));
    const unsigned int l16 = (unsigned int)__half_as_ushort(__float2half(vn - hf));
    const int c = i >> 4, iv = i & 15;
    const bool own = (lg == (iv >> 2));
    const int e = iv & 3, rr = e >> 1, slt = e & 1;
    const unsigned int oh = Vh[c][rr], ol = Vl[c][rr];
    const unsigned int nh = slt ? ((oh & 0x0000FFFFu) | (h16 << 16))
                                : ((oh & 0xFFFF0000u) | h16);
    const unsigned int nl = slt ? ((ol & 0x0000FFFFu) | (l16 << 16))
                                : ((ol & 0xFFFF0000u) | l16);
    Vh[c][rr] = own ? nh : oh;
    Vl[c][rr] = own ? nl : ol;
    // rotate carries
    vp[5] = vp[4]; vp[4] = vp[3]; vp[3] = vp[2]; vp[2] = vp[1]; vp[1] = vn;
  };

  // ---- prologue: Q(0..3) from V_init ----
  v4f D;
  {
    v4f zz = {0.f, 0.f, 0.f, 0.f};
    LOADA(0);
    D = MFMA12(zz);
  }

  // ---- sweeps: 16 groups, MFMA(G+1) pipelined between steps 1 and 2 ----
  for (int it = 0; it < max_iter; ++it) {
    #pragma unroll
    for (int G = 0; G < 16; ++G) {
      LOADA((G + 1) & 15);
      TAIL(4 * G + 0, D[0]);
      TAIL(4 * G + 1, D[1]);
      v4f zz = {0.f, 0.f, 0.f, 0.f};
      v4f Dn = MFMA12(zz);      // uses V with updates through step 4G+1
      TAIL(4 * G + 2, D[2]);
      TAIL(4 * G + 3, D[3]);
      D = Dn;
    }
  }

  // ---- epilogue: f32 shadow -> acos output ----
  if (l < 16) {
    #pragma unroll
    for (int p = 0; p < 4; ++p) {
      float cv = -sh[p];
      cv = fminf(fmaxf(cv, -1.f + 1e-6f), 1.f - 1e-6f);
      out[b * NV + 16 * p + l] = acosf(cv) * (1.f / PI_F);
    }
  }
}

extern "C" void kernel_launch(void* const* d_in, const int* in_sizes, int n_in,
                              void* d_out, int out_size, void* d_ws, size_t ws_size,
                              hipStream_t stream) {
  const float* z = (const float*)d_in[0];
  const float* S = (const float*)d_in[1];
  const float* w = (const float*)d_in[2];
  const float* r = (const float*)d_in[3];
  const int* max_iter = (const int*)d_in[4];
  float* Cg = (float*)d_ws;

  const int nsplit = (ws_size >= (size_t)8 * CBUF * 4) ? 8
                   : (ws_size >= (size_t)4 * CBUF * 4) ? 4 : 1;
  compute_C_kernel<<<dim3(NV, nsplit), 128, 0, stream>>>(S, w, Cg, nsplit);
  mixing_kernel<<<BATCH / 4, 256, 0, stream>>>(z, r, Cg, max_iter,
                                               (float*)d_out, nsplit);
}